// Round 18
// baseline (254.188 us; speedup 1.0000x reference)
//
#include <hip/hip_runtime.h>

typedef unsigned short u16;
typedef unsigned int u32;
typedef __attribute__((ext_vector_type(4))) float f32x4;
typedef __attribute__((ext_vector_type(8))) short bf16x8;

#define T_DIM 2048
#define E_DIM 1024
#define NBATCH 8
#define BK 32
#define BUF 32768    // 256x256 core: A 16KB + B 16KB per K-tile buffer
#define CORE_LDS (3 * BUF)
#define BUFP 24576   // 128x256 core: A 8KB + B 16KB
#define COREP_LDS (3 * BUFP)

struct alignas(8)  U16x4 { u16 x, y, z, w; };
struct alignas(16) F32x4 { float x, y, z, w; };

__device__ __forceinline__ u16 f2bf(float f) {
  u32 u = __float_as_uint(f);
  u += 0x7FFFu + ((u >> 16) & 1u);
  return (u16)(u >> 16);
}

__device__ __forceinline__ void gld16(u16* lds, const u16* g) {
  __builtin_amdgcn_global_load_lds((const __attribute__((address_space(1))) void*)g,
                                   (__attribute__((address_space(3))) void*)lds, 16, 0, 0);
}

// Conflict-free swizzle (r4/r6-verified): byte bits [6:4] ^= bits [9:7].
__device__ __forceinline__ u32 swz7(u32 x) { return x ^ (((x >> 7) & 7u) << 4); }

// Bijective XCD-aware block remap (m204 form).
__device__ __forceinline__ int xcd_swz(int orig, int nwg) {
  int q = nwg >> 3, r = nwg & 7;
  int x = orig & 7, l = orig >> 3;
  return (x < r ? x * (q + 1) : r * (q + 1) + (x - r) * q) + l;
}

#define LGKM0_PIN() do { asm volatile("s_waitcnt lgkmcnt(0)" ::: "memory"); \
                         __builtin_amdgcn_sched_barrier(0); } while (0)

// ---------------------------------------------------------------------------
// 256x256 core (r6/r11-measured best for k_sp): 512 threads (8 waves = 2M x
// 4N), BK=32, 3-buffer ring (96KB), 2 tiles ahead, vmcnt(4)/tile. Minimizes
// staged bytes per output (sp is staging-BW-bound). Requires nK >= 2.
// ---------------------------------------------------------------------------
__device__ __forceinline__ void gemm256(const u16* __restrict__ A, const u16* __restrict__ B,
                                        int lda, int ldb, int nK, char* lds0, f32x4 acc[8][4])
{
  const int tid = threadIdx.x, lane = tid & 63, wave = tid >> 6;
  const int wr = wave >> 2, wc = wave & 3;

  const u16* sAp[2]; const u16* sBp[2];
#pragma unroll
  for (int c = 0; c < 2; ++c) {
    u32 L = (u32)(c * 8192 + tid * 16);
    u32 g = swz7(L);
    sAp[c] = A + (size_t)(g >> 6) * lda + ((g & 63u) >> 1);
    sBp[c] = B + (size_t)(g >> 6) * ldb + ((g & 63u) >> 1);
  }
  const u32 doff = (u32)tid * 16u;

  auto stageA = [&](char* buf, int t) {
#pragma unroll
    for (int c = 0; c < 2; ++c)
      gld16((u16*)(buf + c * 8192 + doff), sAp[c] + t * BK);
  };
  auto stageB = [&](char* buf, int t) {
#pragma unroll
    for (int c = 0; c < 2; ++c)
      gld16((u16*)(buf + 16384 + c * 8192 + doff), sBp[c] + t * BK);
  };

  const u32 cb = (u32)(lane >> 4) * 16u;
  u32 aoff[8], boff[4];
#pragma unroll
  for (int m = 0; m < 8; ++m)
    aoff[m] = swz7((u32)(wr * 128 + m * 16 + (lane & 15)) * 64u + cb);
#pragma unroll
  for (int n = 0; n < 4; ++n)
    boff[n] = 16384u + swz7((u32)(wc * 64 + n * 16 + (lane & 15)) * 64u + cb);

  stageA(lds0, 0); stageB(lds0, 0);
  stageA(lds0 + BUF, 1); stageB(lds0 + BUF, 1);

  int bc = 0;
  bf16x8 a[4], b[4];
  for (int t = 0; t < nK; ++t) {
    char* bufR = lds0 + bc * BUF;
    int b2 = bc + 2; if (b2 >= 3) b2 -= 3;
    char* bufW = lds0 + b2 * BUF;

    if (t + 1 < nK) asm volatile("s_waitcnt vmcnt(4)" ::: "memory");
    else            asm volatile("s_waitcnt vmcnt(0)" ::: "memory");
    __builtin_amdgcn_s_barrier();
    __builtin_amdgcn_sched_barrier(0);

    if (t + 2 < nK) stageA(bufW, t + 2);
#pragma unroll
    for (int j = 0; j < 4; ++j) a[j] = *(const bf16x8*)(bufR + aoff[j]);
#pragma unroll
    for (int n = 0; n < 4; ++n) b[n] = *(const bf16x8*)(bufR + boff[n]);
    LGKM0_PIN();
    __builtin_amdgcn_s_setprio(1);
#pragma unroll
    for (int j = 0; j < 4; ++j)
#pragma unroll
      for (int n = 0; n < 4; ++n)
        acc[j][n] = __builtin_amdgcn_mfma_f32_16x16x32_bf16(a[j], b[n], acc[j][n], 0, 0, 0);
    __builtin_amdgcn_s_setprio(0);
    __builtin_amdgcn_sched_barrier(0);

    if (t + 2 < nK) stageB(bufW, t + 2);
#pragma unroll
    for (int j = 0; j < 4; ++j) a[j] = *(const bf16x8*)(bufR + aoff[4 + j]);
    LGKM0_PIN();
    __builtin_amdgcn_s_setprio(1);
#pragma unroll
    for (int j = 0; j < 4; ++j)
#pragma unroll
      for (int n = 0; n < 4; ++n)
        acc[4 + j][n] = __builtin_amdgcn_mfma_f32_16x16x32_bf16(a[j], b[n], acc[4 + j][n], 0, 0, 0);
    __builtin_amdgcn_s_setprio(0);
    __builtin_amdgcn_sched_barrier(0);

    bc = bc + 1 == 3 ? 0 : bc + 1;
  }
}

// ---------------------------------------------------------------------------
// 128x256 core (r14-proven): 512 threads (8 waves = 2M(64) x 4N(64)), BK=32,
// 3-buffer ring (72KB), 2 tiles ahead, vmcnt(3)/tile. acc[4][4]=64 AGPR;
// VGPR 64 under (512,4) -> 128 unified -> 2 blocks/CU. Requires nK >= 2.
// ---------------------------------------------------------------------------
__device__ __forceinline__ void gemm128n(const u16* __restrict__ A, const u16* __restrict__ B,
                                         int lda, int ldb, int nK, char* lds0, f32x4 acc[4][4])
{
  const int tid = threadIdx.x, lane = tid & 63, wave = tid >> 6;
  const int wr = wave >> 2, wc = wave & 3;

  const u16* sA0; const u16* sBp[2];
  {
    u32 g = swz7((u32)tid * 16u);
    sA0 = A + (size_t)(g >> 6) * lda + ((g & 63u) >> 1);
  }
#pragma unroll
  for (int c = 0; c < 2; ++c) {
    u32 g = swz7((u32)(c * 8192 + tid * 16));
    sBp[c] = B + (size_t)(g >> 6) * ldb + ((g & 63u) >> 1);
  }
  const u32 doff = (u32)tid * 16u;

  auto stageA = [&](char* buf, int t) {
    gld16((u16*)(buf + doff), sA0 + t * BK);
  };
  auto stageB = [&](char* buf, int t) {
#pragma unroll
    for (int c = 0; c < 2; ++c)
      gld16((u16*)(buf + 8192 + c * 8192 + doff), sBp[c] + t * BK);
  };

  const u32 cb = (u32)(lane >> 4) * 16u;
  u32 aoff[4], boff[4];
#pragma unroll
  for (int m = 0; m < 4; ++m)
    aoff[m] = swz7((u32)(wr * 64 + m * 16 + (lane & 15)) * 64u + cb);
#pragma unroll
  for (int n = 0; n < 4; ++n)
    boff[n] = 8192u + swz7((u32)(wc * 64 + n * 16 + (lane & 15)) * 64u + cb);

  stageA(lds0, 0); stageB(lds0, 0);
  stageA(lds0 + BUFP, 1); stageB(lds0 + BUFP, 1);

  int bc = 0;
  bf16x8 a[2], b[4];
  for (int t = 0; t < nK; ++t) {
    char* bufR = lds0 + bc * BUFP;
    int b2 = bc + 2; if (b2 >= 3) b2 -= 3;
    char* bufW = lds0 + b2 * BUFP;

    if (t + 1 < nK) asm volatile("s_waitcnt vmcnt(3)" ::: "memory");
    else            asm volatile("s_waitcnt vmcnt(0)" ::: "memory");
    __builtin_amdgcn_s_barrier();
    __builtin_amdgcn_sched_barrier(0);

    if (t + 2 < nK) stageA(bufW, t + 2);
    a[0] = *(const bf16x8*)(bufR + aoff[0]);
    a[1] = *(const bf16x8*)(bufR + aoff[1]);
#pragma unroll
    for (int n = 0; n < 4; ++n) b[n] = *(const bf16x8*)(bufR + boff[n]);
    LGKM0_PIN();
    __builtin_amdgcn_s_setprio(1);
#pragma unroll
    for (int j = 0; j < 2; ++j)
#pragma unroll
      for (int n = 0; n < 4; ++n)
        acc[j][n] = __builtin_amdgcn_mfma_f32_16x16x32_bf16(a[j], b[n], acc[j][n], 0, 0, 0);
    __builtin_amdgcn_s_setprio(0);
    __builtin_amdgcn_sched_barrier(0);

    if (t + 2 < nK) stageB(bufW, t + 2);
    a[0] = *(const bf16x8*)(bufR + aoff[2]);
    a[1] = *(const bf16x8*)(bufR + aoff[3]);
    LGKM0_PIN();
    __builtin_amdgcn_s_setprio(1);
#pragma unroll
    for (int j = 0; j < 2; ++j)
#pragma unroll
      for (int n = 0; n < 4; ++n)
        acc[2 + j][n] = __builtin_amdgcn_mfma_f32_16x16x32_bf16(a[j], b[n], acc[2 + j][n], 0, 0, 0);
    __builtin_amdgcn_s_setprio(0);
    __builtin_amdgcn_sched_barrier(0);

    bc = bc + 1 == 3 ? 0 : bc + 1;
  }
}

// fp32 -> bf16 convert
__global__ __launch_bounds__(256) void k_cvt(const float* __restrict__ in, u16* __restrict__ out, int n4)
{
  int i = blockIdx.x * 256 + threadIdx.x;
  if (i >= n4) return;
  F32x4 v = *(const F32x4*)&in[(size_t)i * 4];
  U16x4 o;
  o.x = f2bf(v.x); o.y = f2bf(v.y); o.z = f2bf(v.z); o.w = f2bf(v.w);
  *(U16x4*)&out[(size_t)i * 4] = o;
}

// QKV projection (r14/r17 verbatim): 128x256 tiles, bf16 A via gld16, 2 blocks/CU.
__global__ __launch_bounds__(512, 4) void k_qkv(const u16* __restrict__ Xb, const u16* __restrict__ Wb,
                                                const float* __restrict__ bias,
                                                u16* __restrict__ Q, u16* __restrict__ Kmat,
                                                u16* __restrict__ Vt)
{
  __shared__ __align__(16) char lds[COREP_LDS];
  const int wg = xcd_swz(blockIdx.x, gridDim.x);
  const int my = wg / 12, nx = wg % 12;
  const int m0 = my * 128, n0 = nx * 256;
  const int tid = threadIdx.x, lane = tid & 63, wave = tid >> 6;
  const int wr = wave >> 2, wc = wave & 3;
  f32x4 acc[4][4] = {};
  gemm128n(Xb + (size_t)m0 * E_DIM, Wb + (size_t)n0 * E_DIM, E_DIM, E_DIM, E_DIM / BK, lds, acc);
  __syncthreads();

  char* wsl = lds + wave * 8192;
  const int region = nx >> 2;  // 0=Q 1=K 2=V
  const int nlb = (n0 & (E_DIM - 1)) + wc * 64;
  const int g4 = (lane >> 4) << 2;

  if (region < 2) {
    u16* dst = region ? Kmat : Q;
#pragma unroll
    for (int n = 0; n < 4; ++n) {
      const float bn = bias[n0 + wc * 64 + n * 16 + (lane & 15)];
#pragma unroll
      for (int m = 0; m < 4; ++m)
#pragma unroll
        for (int r = 0; r < 4; ++r) {
          const int rl = m * 16 + g4 + r;
          const int cl = n * 16 + (lane & 15);
          u32 byte = (u32)(rl * 128 + cl * 2) ^ (u32)((rl & 7) << 4);
          *(u16*)(wsl + byte) = f2bf(acc[m][n][r] + bn);
        }
    }
    asm volatile("s_waitcnt lgkmcnt(0)" ::: "memory");  // own slice only
    const int rowb = m0 + wr * 64;
#pragma unroll
    for (int it = 0; it < 8; ++it) {
      const int rl = it * 8 + (lane >> 3);
      const int c16 = lane & 7;
      u32 byte = (u32)(rl * 128 + c16 * 16) ^ (u32)((rl & 7) << 4);
      bf16x8 v = *(const bf16x8*)(wsl + byte);
      *(bf16x8*)&dst[(size_t)(rowb + rl) * E_DIM + nlb + c16 * 8] = v;
    }
  } else {
    const int bl = m0 >> 11;
    const int tb = (m0 & (T_DIM - 1)) + wr * 64;
#pragma unroll
    for (int n = 0; n < 4; ++n) {
      const float bn = bias[n0 + wc * 64 + n * 16 + (lane & 15)];
      const int e_l = n * 16 + (lane & 15);
#pragma unroll
      for (int m = 0; m < 4; ++m)
#pragma unroll
        for (int r = 0; r < 4; ++r) {
          const int tl = m * 16 + g4 + r;
          u32 byte = (u32)(e_l * 128 + tl * 2) ^ (u32)((e_l & 7) << 4);
          *(u16*)(wsl + byte) = f2bf(acc[m][n][r] + bn);
        }
    }
    asm volatile("s_waitcnt lgkmcnt(0)" ::: "memory");
#pragma unroll
    for (int it = 0; it < 8; ++it) {
      const int e_l = it * 8 + (lane >> 3);
      const int t16 = lane & 7;
      u32 byte = (u32)(e_l * 128 + t16 * 16) ^ (u32)((e_l & 7) << 4);
      bf16x8 v = *(const bf16x8*)(wsl + byte);
      *(bf16x8*)&Vt[((size_t)bl * E_DIM + nlb + e_l) * T_DIM + tb + t16 * 8] = v;
    }
  }
}

// Fused causal scores + no-max softmax (r11 verbatim, 256x256): lowest
// staged-bytes/output form; sp is staging-BW-bound. P' = exp(min(S,60)) bf16
// (masked -> 0), lc per (row, 256-chunk).
__global__ __launch_bounds__(512, 2) void k_sp(const u16* __restrict__ Q, const u16* __restrict__ Kmat,
                                               u16* __restrict__ P, float* __restrict__ lc)
{
  __shared__ __align__(16) char lds[CORE_LDS];
  const int wg = xcd_swz(blockIdx.x, gridDim.x);
  const int b = wg / 36;
  const int ti = wg % 36;
  int iq = 0;
  while ((iq + 1) * (iq + 2) / 2 <= ti) ++iq;
  const int ik = ti - iq * (iq + 1) / 2;
  const int tid = threadIdx.x, lane = tid & 63, wave = tid >> 6;
  const int wr = wave >> 2, wc = wave & 3;
  f32x4 acc[8][4] = {};
  const u16* Qp = Q    + (size_t)b * T_DIM * E_DIM + (size_t)iq * 256 * E_DIM;
  const u16* Kp = Kmat + (size_t)b * T_DIM * E_DIM + (size_t)ik * 256 * E_DIM;
  gemm256(Qp, Kp, E_DIM, E_DIM, E_DIM / BK, lds, acc);
  __syncthreads();

  const float scale = 0.03125f;  // 1/sqrt(1024)
  if (ik == iq) {
#pragma unroll
    for (int n = 0; n < 4; ++n) {
      const int kg = wc * 64 + n * 16 + (lane & 15);
#pragma unroll
      for (int m = 0; m < 8; ++m) {
        const int qg0 = wr * 128 + m * 16 + ((lane >> 4) << 2);
#pragma unroll
        for (int r = 0; r < 4; ++r)
          acc[m][n][r] = (kg > qg0 + r) ? 0.f
                        : __expf(fminf(acc[m][n][r] * scale, 60.f));
      }
    }
  } else {
#pragma unroll
    for (int m = 0; m < 8; ++m)
#pragma unroll
      for (int n = 0; n < 4; ++n)
#pragma unroll
        for (int r = 0; r < 4; ++r)
          acc[m][n][r] = __expf(fminf(acc[m][n][r] * scale, 60.f));
  }

  // row sums: in-wave (16-lane groups) + cross-wave via LDS
  float* red2 = (float*)lds;          // [4][256]
  float Ls[8][4];
#pragma unroll
  for (int m = 0; m < 8; ++m)
#pragma unroll
    for (int r = 0; r < 4; ++r) {
      float s = acc[m][0][r] + acc[m][1][r] + acc[m][2][r] + acc[m][3][r];
#pragma unroll
      for (int off = 1; off <= 8; off <<= 1) s += __shfl_xor(s, off, 64);
      Ls[m][r] = s;
    }
  if ((lane & 15) == 0) {
#pragma unroll
    for (int m = 0; m < 8; ++m)
#pragma unroll
      for (int r = 0; r < 4; ++r)
        red2[wc * 256 + wr * 128 + m * 16 + ((lane >> 4) << 2) + r] = Ls[m][r];
  }
  __syncthreads();
  if (wc == 0 && (lane & 15) == 0) {
#pragma unroll
    for (int m = 0; m < 8; ++m)
#pragma unroll
      for (int r = 0; r < 4; ++r) {
        const int row = wr * 128 + m * 16 + ((lane >> 4) << 2) + r;
        const float l = red2[row] + red2[256 + row] + red2[512 + row] + red2[768 + row];
        lc[((size_t)b * T_DIM + iq * 256 + row) * 8 + ik] = l;
      }
  }
  __syncthreads();   // red2 reads done before slices overwrite lds

  // P write via per-wave LDS slice (coalesced 128B segments)
  u16* Pb = P + (size_t)b * T_DIM * T_DIM;
  char* wsl = lds + 16384 + wave * 8192;
#pragma unroll
  for (int p = 0; p < 2; ++p) {
#pragma unroll
    for (int n = 0; n < 4; ++n)
#pragma unroll
      for (int mm = 0; mm < 4; ++mm)
#pragma unroll
        for (int r = 0; r < 4; ++r) {
          const int rl = mm * 16 + ((lane >> 4) << 2) + r;
          const int cl = n * 16 + (lane & 15);
          u32 byte = (u32)(rl * 128 + cl * 2) ^ (u32)((rl & 7) << 4);
          *(u16*)(wsl + byte) = f2bf(acc[p * 4 + mm][n][r]);
        }
    asm volatile("s_waitcnt lgkmcnt(0)" ::: "memory");
    const int rowb = iq * 256 + wr * 128 + p * 64;
    const int colb = ik * 256 + wc * 64;
#pragma unroll
    for (int it = 0; it < 8; ++it) {
      const int rl = it * 8 + (lane >> 3);
      const int c16 = lane & 7;
      u32 byte = (u32)(rl * 128 + c16 * 16) ^ (u32)((rl & 7) << 4);
      bf16x8 v = *(const bf16x8*)(wsl + byte);
      *(bf16x8*)&Pb[(size_t)(rowb + rl) * T_DIM + colb + c16 * 8] = v;
    }
    if (p == 0) asm volatile("s_waitcnt lgkmcnt(0)" ::: "memory");
  }
}

// Per-row finish: fin = 1 / sum_c l_c  (256-chunks, stride 8)
__global__ __launch_bounds__(256) void k_finish(const float* __restrict__ lc, float* __restrict__ fin)
{
  const int rg = blockIdx.x * 256 + threadIdx.x;
  const int q = rg & (T_DIM - 1);
  const int C = (q >> 8) + 1;
  const float* l = lc + (size_t)rg * 8;
  float L = 0.f;
  for (int c = 0; c < C; ++c) L += l[c];
  fin[rg] = 1.f / L;
}

// PV (r17 verbatim): 128-row q-tiles, paired (pr, 15-pr) -> uniform 9
// chunk-gemms; (512,4) => 2 blocks/CU.
__global__ __launch_bounds__(512, 4) void k_pv(const u16* __restrict__ P, const u16* __restrict__ Vt,
                                               const float* __restrict__ fin,
                                               float* __restrict__ out, int batch0)
{
  __shared__ __align__(16) char lds[COREP_LDS];
  const int wg = xcd_swz(blockIdx.x, gridDim.x);
  const int bl = wg >> 5, rr = wg & 31;
  const int pr = rr >> 2, ie = rr & 3;
  const int tid = threadIdx.x, lane = tid & 63, wave = tid >> 6;
  const int wr = wave >> 2, wc = wave & 3;

  const u16* Bp = Vt + (size_t)bl * E_DIM * T_DIM + (size_t)ie * 256 * T_DIM;

#pragma unroll
  for (int mem = 0; mem < 2; ++mem) {
    const int iq = mem ? 15 - pr : pr;
    const int nch = (iq >> 1) + 1;

    __syncthreads();
    f32x4 acc[4][4] = {};
    const u16* Ap = P + (size_t)bl * T_DIM * T_DIM + (size_t)iq * 128 * T_DIM;
    gemm128n(Ap, Bp, T_DIM, T_DIM, nch * 8, lds, acc);

#pragma unroll
    for (int m = 0; m < 4; ++m) {
      const int qg0 = iq * 128 + wr * 64 + m * 16 + ((lane >> 4) << 2);
#pragma unroll
      for (int r = 0; r < 4; ++r) {
        const int qg = qg0 + r;
        const float il = fin[bl * T_DIM + qg];
        float* orow = out + ((size_t)(batch0 + bl) * T_DIM + qg) * E_DIM;
#pragma unroll
        for (int n = 0; n < 4; ++n) {
          const int eg = ie * 256 + wc * 64 + n * 16 + (lane & 15);
          orow[eg] = acc[m][n][r] * il;
        }
      }
    }
  }
}

extern "C" void kernel_launch(void* const* d_in, const int* in_sizes, int n_in,
                              void* d_out, int out_size, void* d_ws, size_t ws_size,
                              hipStream_t stream)
{
  const float* x    = (const float*)d_in[0];  // [8, 2048, 1024]
  const float* W    = (const float*)d_in[1];  // [3072, 1024]
  const float* bias = (const float*)d_in[2];  // [3072]
  float* out = (float*)d_out;

  char* ws = (char*)d_ws;
  const size_t ALIGN = 256;
  auto up = [&](size_t v) { return (v + ALIGN - 1) & ~(ALIGN - 1); };

  const size_t szWb = up((size_t)3 * E_DIM * E_DIM * 2);
  const size_t szX  = up((size_t)T_DIM * E_DIM * 2);       // bf16 [T,E] per batch
  const size_t szP  = up((size_t)T_DIM * T_DIM * 2);       // bf16 P' per batch
  const size_t szM  = up((size_t)T_DIM * 8 * 4);           // lc per batch
  const size_t szI  = up((size_t)T_DIM * 4);               // fin per batch
  const size_t perB = 4 * szX + szP + szM + szI;            // Xb,Q,K,Vt + P + lc + fin

  int nb = 1;
  for (int cand = NBATCH; cand >= 1; --cand) {
    if (szWb + (size_t)cand * perB <= ws_size) { nb = cand; break; }
  }

  u16* Wb = (u16*)ws;
  {
    int n4 = 3 * E_DIM * E_DIM / 4;
    k_cvt<<<(n4 + 255) / 256, 256, 0, stream>>>(W, Wb, n4);
  }

  for (int b0 = 0; b0 < NBATCH; b0 += nb) {
    const int nbc = (NBATCH - b0 < nb) ? (NBATCH - b0) : nb;
    size_t o = szWb;
    u16* Xb    = (u16*)(ws + o);   o += (size_t)nbc * szX;
    u16* Qb    = (u16*)(ws + o);   o += (size_t)nbc * szX;
    u16* Kb    = (u16*)(ws + o);   o += (size_t)nbc * szX;
    u16* Vt    = (u16*)(ws + o);   o += (size_t)nbc * szX;
    u16* P     = (u16*)(ws + o);   o += (size_t)nbc * szP;
    float* lcA = (float*)(ws + o); o += (size_t)nbc * szM;
    float* fin = (float*)(ws + o); o += (size_t)nbc * szI;

    {
      int n4 = nbc * T_DIM * E_DIM / 4;
      k_cvt<<<(n4 + 255) / 256, 256, 0, stream>>>(x + (size_t)b0 * T_DIM * E_DIM, Xb, n4);
    }
    k_qkv<<<dim3(192 * nbc), 512, 0, stream>>>(Xb, Wb, bias, Qb, Kb, Vt);
    k_sp<<<dim3(36 * nbc), 512, 0, stream>>>(Qb, Kb, P, lcA);
    k_finish<<<dim3(nbc * T_DIM / 256), 256, 0, stream>>>(lcA, fin);
    k_pv<<<dim3(32 * nbc), 512, 0, stream>>>(P, Vt, fin, out, b0);
  }
}

// Round 19
// 237.703 us; speedup vs baseline: 1.0693x; 1.0693x over previous
//
#include <hip/hip_runtime.h>

typedef unsigned short u16;
typedef unsigned int u32;
typedef __attribute__((ext_vector_type(4))) float f32x4;
typedef __attribute__((ext_vector_type(8))) short bf16x8;

#define T_DIM 2048
#define E_DIM 1024
#define NBATCH 8
#define BK 32
#define BUFP 24576   // 128x256 core: A 8KB + B 16KB
#define COREP_LDS (3 * BUFP)

struct alignas(8)  U16x4 { u16 x, y, z, w; };
struct alignas(16) F32x4 { float x, y, z, w; };

__device__ __forceinline__ u16 f2bf(float f) {
  u32 u = __float_as_uint(f);
  u += 0x7FFFu + ((u >> 16) & 1u);
  return (u16)(u >> 16);
}

__device__ __forceinline__ void gld16(u16* lds, const u16* g) {
  __builtin_amdgcn_global_load_lds((const __attribute__((address_space(1))) void*)g,
                                   (__attribute__((address_space(3))) void*)lds, 16, 0, 0);
}

// Conflict-free swizzle (r4/r6-verified): byte bits [6:4] ^= bits [9:7].
__device__ __forceinline__ u32 swz7(u32 x) { return x ^ (((x >> 7) & 7u) << 4); }

// Bijective XCD-aware block remap (m204 form).
__device__ __forceinline__ int xcd_swz(int orig, int nwg) {
  int q = nwg >> 3, r = nwg & 7;
  int x = orig & 7, l = orig >> 3;
  return (x < r ? x * (q + 1) : r * (q + 1) + (x - r) * q) + l;
}

#define LGKM0_PIN() do { asm volatile("s_waitcnt lgkmcnt(0)" ::: "memory"); \
                         __builtin_amdgcn_sched_barrier(0); } while (0)

// ---------------------------------------------------------------------------
// 128x256 core (r14-proven): 512 threads (8 waves = 2M(64) x 4N(64)), BK=32,
// 3-buffer ring (72KB), 2 tiles ahead, vmcnt(3)/tile. acc[4][4]=64 AGPR;
// VGPR 64 under (512,4) -> 128 unified -> 2 blocks/CU. Requires nK >= 2.
// ---------------------------------------------------------------------------
__device__ __forceinline__ void gemm128n(const u16* __restrict__ A, const u16* __restrict__ B,
                                         int lda, int ldb, int nK, char* lds0, f32x4 acc[4][4])
{
  const int tid = threadIdx.x, lane = tid & 63, wave = tid >> 6;
  const int wr = wave >> 2, wc = wave & 3;

  const u16* sA0; const u16* sBp[2];
  {
    u32 g = swz7((u32)tid * 16u);
    sA0 = A + (size_t)(g >> 6) * lda + ((g & 63u) >> 1);
  }
#pragma unroll
  for (int c = 0; c < 2; ++c) {
    u32 g = swz7((u32)(c * 8192 + tid * 16));
    sBp[c] = B + (size_t)(g >> 6) * ldb + ((g & 63u) >> 1);
  }
  const u32 doff = (u32)tid * 16u;

  auto stageA = [&](char* buf, int t) {
    gld16((u16*)(buf + doff), sA0 + t * BK);
  };
  auto stageB = [&](char* buf, int t) {
#pragma unroll
    for (int c = 0; c < 2; ++c)
      gld16((u16*)(buf + 8192 + c * 8192 + doff), sBp[c] + t * BK);
  };

  const u32 cb = (u32)(lane >> 4) * 16u;
  u32 aoff[4], boff[4];
#pragma unroll
  for (int m = 0; m < 4; ++m)
    aoff[m] = swz7((u32)(wr * 64 + m * 16 + (lane & 15)) * 64u + cb);
#pragma unroll
  for (int n = 0; n < 4; ++n)
    boff[n] = 8192u + swz7((u32)(wc * 64 + n * 16 + (lane & 15)) * 64u + cb);

  stageA(lds0, 0); stageB(lds0, 0);
  stageA(lds0 + BUFP, 1); stageB(lds0 + BUFP, 1);

  int bc = 0;
  bf16x8 a[2], b[4];
  for (int t = 0; t < nK; ++t) {
    char* bufR = lds0 + bc * BUFP;
    int b2 = bc + 2; if (b2 >= 3) b2 -= 3;
    char* bufW = lds0 + b2 * BUFP;

    if (t + 1 < nK) asm volatile("s_waitcnt vmcnt(3)" ::: "memory");
    else            asm volatile("s_waitcnt vmcnt(0)" ::: "memory");
    __builtin_amdgcn_s_barrier();
    __builtin_amdgcn_sched_barrier(0);

    if (t + 2 < nK) stageA(bufW, t + 2);
    a[0] = *(const bf16x8*)(bufR + aoff[0]);
    a[1] = *(const bf16x8*)(bufR + aoff[1]);
#pragma unroll
    for (int n = 0; n < 4; ++n) b[n] = *(const bf16x8*)(bufR + boff[n]);
    LGKM0_PIN();
    __builtin_amdgcn_s_setprio(1);
#pragma unroll
    for (int j = 0; j < 2; ++j)
#pragma unroll
      for (int n = 0; n < 4; ++n)
        acc[j][n] = __builtin_amdgcn_mfma_f32_16x16x32_bf16(a[j], b[n], acc[j][n], 0, 0, 0);
    __builtin_amdgcn_s_setprio(0);
    __builtin_amdgcn_sched_barrier(0);

    if (t + 2 < nK) stageB(bufW, t + 2);
    a[0] = *(const bf16x8*)(bufR + aoff[2]);
    a[1] = *(const bf16x8*)(bufR + aoff[3]);
    LGKM0_PIN();
    __builtin_amdgcn_s_setprio(1);
#pragma unroll
    for (int j = 0; j < 2; ++j)
#pragma unroll
      for (int n = 0; n < 4; ++n)
        acc[2 + j][n] = __builtin_amdgcn_mfma_f32_16x16x32_bf16(a[j], b[n], acc[2 + j][n], 0, 0, 0);
    __builtin_amdgcn_s_setprio(0);
    __builtin_amdgcn_sched_barrier(0);

    bc = bc + 1 == 3 ? 0 : bc + 1;
  }
}

// fp32 -> bf16 convert
__global__ __launch_bounds__(256) void k_cvt(const float* __restrict__ in, u16* __restrict__ out, int n4)
{
  int i = blockIdx.x * 256 + threadIdx.x;
  if (i >= n4) return;
  F32x4 v = *(const F32x4*)&in[(size_t)i * 4];
  U16x4 o;
  o.x = f2bf(v.x); o.y = f2bf(v.y); o.z = f2bf(v.z); o.w = f2bf(v.w);
  *(U16x4*)&out[(size_t)i * 4] = o;
}

// QKV projection: 128x256 tiles, bf16 A via gld16, 2 blocks/CU.
__global__ __launch_bounds__(512, 4) void k_qkv(const u16* __restrict__ Xb, const u16* __restrict__ Wb,
                                                const float* __restrict__ bias,
                                                u16* __restrict__ Q, u16* __restrict__ Kmat,
                                                u16* __restrict__ Vt)
{
  __shared__ __align__(16) char lds[COREP_LDS];
  const int wg = xcd_swz(blockIdx.x, gridDim.x);
  const int my = wg / 12, nx = wg % 12;
  const int m0 = my * 128, n0 = nx * 256;
  const int tid = threadIdx.x, lane = tid & 63, wave = tid >> 6;
  const int wr = wave >> 2, wc = wave & 3;
  f32x4 acc[4][4] = {};
  gemm128n(Xb + (size_t)m0 * E_DIM, Wb + (size_t)n0 * E_DIM, E_DIM, E_DIM, E_DIM / BK, lds, acc);
  __syncthreads();

  char* wsl = lds + wave * 8192;
  const int region = nx >> 2;  // 0=Q 1=K 2=V
  const int nlb = (n0 & (E_DIM - 1)) + wc * 64;
  const int g4 = (lane >> 4) << 2;

  if (region < 2) {
    u16* dst = region ? Kmat : Q;
#pragma unroll
    for (int n = 0; n < 4; ++n) {
      const float bn = bias[n0 + wc * 64 + n * 16 + (lane & 15)];
#pragma unroll
      for (int m = 0; m < 4; ++m)
#pragma unroll
        for (int r = 0; r < 4; ++r) {
          const int rl = m * 16 + g4 + r;
          const int cl = n * 16 + (lane & 15);
          u32 byte = (u32)(rl * 128 + cl * 2) ^ (u32)((rl & 7) << 4);
          *(u16*)(wsl + byte) = f2bf(acc[m][n][r] + bn);
        }
    }
    asm volatile("s_waitcnt lgkmcnt(0)" ::: "memory");  // own slice only
    const int rowb = m0 + wr * 64;
#pragma unroll
    for (int it = 0; it < 8; ++it) {
      const int rl = it * 8 + (lane >> 3);
      const int c16 = lane & 7;
      u32 byte = (u32)(rl * 128 + c16 * 16) ^ (u32)((rl & 7) << 4);
      bf16x8 v = *(const bf16x8*)(wsl + byte);
      *(bf16x8*)&dst[(size_t)(rowb + rl) * E_DIM + nlb + c16 * 8] = v;
    }
  } else {
    const int bl = m0 >> 11;
    const int tb = (m0 & (T_DIM - 1)) + wr * 64;
#pragma unroll
    for (int n = 0; n < 4; ++n) {
      const float bn = bias[n0 + wc * 64 + n * 16 + (lane & 15)];
      const int e_l = n * 16 + (lane & 15);
#pragma unroll
      for (int m = 0; m < 4; ++m)
#pragma unroll
        for (int r = 0; r < 4; ++r) {
          const int tl = m * 16 + g4 + r;
          u32 byte = (u32)(e_l * 128 + tl * 2) ^ (u32)((e_l & 7) << 4);
          *(u16*)(wsl + byte) = f2bf(acc[m][n][r] + bn);
        }
    }
    asm volatile("s_waitcnt lgkmcnt(0)" ::: "memory");
#pragma unroll
    for (int it = 0; it < 8; ++it) {
      const int e_l = it * 8 + (lane >> 3);
      const int t16 = lane & 7;
      u32 byte = (u32)(e_l * 128 + t16 * 16) ^ (u32)((e_l & 7) << 4);
      bf16x8 v = *(const bf16x8*)(wsl + byte);
      *(bf16x8*)&Vt[((size_t)bl * E_DIM + nlb + e_l) * T_DIM + tb + t16 * 8] = v;
    }
  }
}

// Fused causal scores + no-max softmax: 128-row q-tiles x 256-col chunks.
// P' = exp(min(S,60)) bf16 (masked -> 0), lc per (row, 256-chunk).
__global__ __launch_bounds__(512, 4) void k_sp(const u16* __restrict__ Q, const u16* __restrict__ Kmat,
                                               u16* __restrict__ P, float* __restrict__ lc)
{
  __shared__ __align__(16) char lds[COREP_LDS];
  const int wg = xcd_swz(blockIdx.x, gridDim.x);
  const int b = wg / 72;
  int ti = wg % 72;
  int iq = 0;
  while (ti >= (iq >> 1) + 1) { ti -= (iq >> 1) + 1; ++iq; }
  const int ik = ti;
  const int tid = threadIdx.x, lane = tid & 63, wave = tid >> 6;
  const int wr = wave >> 2, wc = wave & 3;
  const int g4 = (lane >> 4) << 2;
  f32x4 acc[4][4] = {};
  const u16* Qp = Q    + (size_t)b * T_DIM * E_DIM + (size_t)iq * 128 * E_DIM;
  const u16* Kp = Kmat + (size_t)b * T_DIM * E_DIM + (size_t)ik * 256 * E_DIM;
  gemm128n(Qp, Kp, E_DIM, E_DIM, E_DIM / BK, lds, acc);
  __syncthreads();

  const float scale = 0.03125f;  // 1/sqrt(1024)
  const bool diag = (ik == (iq >> 1));
  const int diagoff = iq * 128 - ik * 256;  // 0 or 128
#pragma unroll
  for (int n = 0; n < 4; ++n) {
    const int cl = wc * 64 + n * 16 + (lane & 15);
#pragma unroll
    for (int m = 0; m < 4; ++m) {
      const int rl0 = wr * 64 + m * 16 + g4;
#pragma unroll
      for (int r = 0; r < 4; ++r) {
        if (diag && cl > diagoff + rl0 + r) acc[m][n][r] = 0.f;
        else acc[m][n][r] = __expf(fminf(acc[m][n][r] * scale, 60.f));
      }
    }
  }

  float* red2 = (float*)lds;          // [4][128]
  float Ls[4][4];
#pragma unroll
  for (int m = 0; m < 4; ++m)
#pragma unroll
    for (int r = 0; r < 4; ++r) {
      float s = acc[m][0][r] + acc[m][1][r] + acc[m][2][r] + acc[m][3][r];
#pragma unroll
      for (int off = 1; off <= 8; off <<= 1) s += __shfl_xor(s, off, 64);
      Ls[m][r] = s;
    }
  if ((lane & 15) == 0) {
#pragma unroll
    for (int m = 0; m < 4; ++m)
#pragma unroll
      for (int r = 0; r < 4; ++r)
        red2[wc * 128 + wr * 64 + m * 16 + g4 + r] = Ls[m][r];
  }
  __syncthreads();
  if (wc == 0 && (lane & 15) == 0) {
#pragma unroll
    for (int m = 0; m < 4; ++m)
#pragma unroll
      for (int r = 0; r < 4; ++r) {
        const int row = wr * 64 + m * 16 + g4 + r;
        const float l = red2[row] + red2[128 + row] + red2[256 + row] + red2[384 + row];
        lc[((size_t)b * T_DIM + iq * 128 + row) * 8 + ik] = l;
      }
  }
  __syncthreads();

  u16* Pb = P + (size_t)b * T_DIM * T_DIM;
  char* wsl = lds + wave * 8192;
#pragma unroll
  for (int n = 0; n < 4; ++n)
#pragma unroll
    for (int m = 0; m < 4; ++m)
#pragma unroll
      for (int r = 0; r < 4; ++r) {
        const int rl = m * 16 + g4 + r;
        const int cl = n * 16 + (lane & 15);
        u32 byte = (u32)(rl * 128 + cl * 2) ^ (u32)((rl & 7) << 4);
        *(u16*)(wsl + byte) = f2bf(acc[m][n][r]);
      }
  asm volatile("s_waitcnt lgkmcnt(0)" ::: "memory");
  const int rowb = iq * 128 + wr * 64;
  const int colb = ik * 256 + wc * 64;
#pragma unroll
  for (int it = 0; it < 8; ++it) {
    const int rl = it * 8 + (lane >> 3);
    const int c16 = lane & 7;
    u32 byte = (u32)(rl * 128 + c16 * 16) ^ (u32)((rl & 7) << 4);
    bf16x8 v = *(const bf16x8*)(wsl + byte);
    *(bf16x8*)&Pb[(size_t)(rowb + rl) * T_DIM + colb + c16 * 8] = v;
  }
}

// Per-row finish: fin = 1 / sum_c l_c  (256-chunks, stride 8)
__global__ __launch_bounds__(256) void k_finish(const float* __restrict__ lc, float* __restrict__ fin)
{
  const int rg = blockIdx.x * 256 + threadIdx.x;
  const int q = rg & (T_DIM - 1);
  const int C = (q >> 8) + 1;
  const float* l = lc + (size_t)rg * 8;
  float L = 0.f;
  for (int c = 0; c < C; ++c) L += l[c];
  fin[rg] = 1.f / L;
}

// PV: 128-row q-tiles, paired (pr, 15-pr) -> uniform 9 chunk-gemms; (512,4)
// => 2 blocks/CU.
__global__ __launch_bounds__(512, 4) void k_pv(const u16* __restrict__ P, const u16* __restrict__ Vt,
                                               const float* __restrict__ fin,
                                               float* __restrict__ out, int batch0)
{
  __shared__ __align__(16) char lds[COREP_LDS];
  const int wg = xcd_swz(blockIdx.x, gridDim.x);
  const int bl = wg >> 5, rr = wg & 31;
  const int pr = rr >> 2, ie = rr & 3;
  const int tid = threadIdx.x, lane = tid & 63, wave = tid >> 6;
  const int wr = wave >> 2, wc = wave & 3;

  const u16* Bp = Vt + (size_t)bl * E_DIM * T_DIM + (size_t)ie * 256 * T_DIM;

#pragma unroll
  for (int mem = 0; mem < 2; ++mem) {
    const int iq = mem ? 15 - pr : pr;
    const int nch = (iq >> 1) + 1;

    __syncthreads();
    f32x4 acc[4][4] = {};
    const u16* Ap = P + (size_t)bl * T_DIM * T_DIM + (size_t)iq * 128 * T_DIM;
    gemm128n(Ap, Bp, T_DIM, T_DIM, nch * 8, lds, acc);

#pragma unroll
    for (int m = 0; m < 4; ++m) {
      const int qg0 = iq * 128 + wr * 64 + m * 16 + ((lane >> 4) << 2);
#pragma unroll
      for (int r = 0; r < 4; ++r) {
        const int qg = qg0 + r;
        const float il = fin[bl * T_DIM + qg];
        float* orow = out + ((size_t)(batch0 + bl) * T_DIM + qg) * E_DIM;
#pragma unroll
        for (int n = 0; n < 4; ++n) {
          const int eg = ie * 256 + wc * 64 + n * 16 + (lane & 15);
          orow[eg] = acc[m][n][r] * il;
        }
      }
    }
  }
}

extern "C" void kernel_launch(void* const* d_in, const int* in_sizes, int n_in,
                              void* d_out, int out_size, void* d_ws, size_t ws_size,
                              hipStream_t stream)
{
  const float* x    = (const float*)d_in[0];  // [8, 2048, 1024]
  const float* W    = (const float*)d_in[1];  // [3072, 1024]
  const float* bias = (const float*)d_in[2];  // [3072]
  float* out = (float*)d_out;

  char* ws = (char*)d_ws;
  const size_t ALIGN = 256;
  auto up = [&](size_t v) { return (v + ALIGN - 1) & ~(ALIGN - 1); };

  const size_t szWb = up((size_t)3 * E_DIM * E_DIM * 2);
  const size_t szX  = up((size_t)T_DIM * E_DIM * 2);       // bf16 [T,E] per batch
  const size_t szP  = up((size_t)T_DIM * T_DIM * 2);       // bf16 P' per batch
  const size_t szM  = up((size_t)T_DIM * 8 * 4);           // lc per batch
  const size_t szI  = up((size_t)T_DIM * 4);               // fin per batch
  const size_t perB = 4 * szX + szP + szM + szI;            // Xb,Q,K,Vt + P + lc + fin

  int nb = 1;
  for (int cand = NBATCH; cand >= 1; --cand) {
    if (szWb + (size_t)cand * perB <= ws_size) { nb = cand; break; }
  }

  u16* Wb = (u16*)ws;
  {
    int n4 = 3 * E_DIM * E_DIM / 4;
    k_cvt<<<(n4 + 255) / 256, 256, 0, stream>>>(W, Wb, n4);
  }

  for (int b0 = 0; b0 < NBATCH; b0 += nb) {
    const int nbc = (NBATCH - b0 < nb) ? (NBATCH - b0) : nb;
    size_t o = szWb;
    u16* Xb    = (u16*)(ws + o);   o += (size_t)nbc * szX;
    u16* Qb    = (u16*)(ws + o);   o += (size_t)nbc * szX;
    u16* Kb    = (u16*)(ws + o);   o += (size_t)nbc * szX;
    u16* Vt    = (u16*)(ws + o);   o += (size_t)nbc * szX;
    u16* P     = (u16*)(ws + o);   o += (size_t)nbc * szP;
    float* lcA = (float*)(ws + o); o += (size_t)nbc * szM;
    float* fin = (float*)(ws + o); o += (size_t)nbc * szI;

    {
      int n4 = nbc * T_DIM * E_DIM / 4;
      k_cvt<<<(n4 + 255) / 256, 256, 0, stream>>>(x + (size_t)b0 * T_DIM * E_DIM, Xb, n4);
    }
    k_qkv<<<dim3(192 * nbc), 512, 0, stream>>>(Xb, Wb, bias, Qb, Kb, Vt);
    k_sp<<<dim3(72 * nbc), 512, 0, stream>>>(Qb, Kb, P, lcA);
    k_finish<<<dim3(nbc * T_DIM / 256), 256, 0, stream>>>(lcA, fin);
    k_pv<<<dim3(32 * nbc), 512, 0, stream>>>(P, Vt, fin, out, b0);
  }
}